// Round 4
// baseline (286.959 us; speedup 1.0000x reference)
//
#include <hip/hip_runtime.h>
#include <math.h>

#define NRES 384
#define NH   12
#define WLc 0.5773502691896258f
#define WCc 0.23570226039551587f

typedef __attribute__((ext_vector_type(8))) _Float16 half8;
typedef __attribute__((ext_vector_type(4))) float f32x4;

// workspace layout (float offsets)
#define OFF_P    0           // f32 [384][1152] proj out
#define OFF_QE   442368      // f32 [384][384]  (i, h*32+c)
#define OFF_KE   589824      // f32 [12][384][32]
#define OFF_VET  737280      // f16 [12][48][384]
#define OFF_SH   847872      // f16 [384][384]  s
#define OFF_WCT  921600      // f16 [1152][384] Wcat^T
#define OFF_BCT  1142784     // f32 [1152]
#define OFF_WOT  1143936     // f16 [384][2112] Wo^T
#define OFF_WBT  1549440     // f16 [16][128]  WLc*Wb^T (rows>=12 zero)
#define OFF_CAT  1550464     // f16 [384][2112] concat
#define OFF_ATT  1955968     // f16 [12][384][384] att
// end 2398336 f32 = 9.6 MB

// ---------------------------------------------------------------------------
// K0: pack. s->f16 flat; Wcat^T & Wo^T via LDS-tiled transpose; WbT; bcat.
// grid 451 blocks x 256
// ---------------------------------------------------------------------------
__global__ __launch_bounds__(256) void pack_kernel(
    const float* __restrict__ s,
    const float* __restrict__ Wq,  const float* __restrict__ bq,
    const float* __restrict__ Wk,  const float* __restrict__ bk,
    const float* __restrict__ Wv,  const float* __restrict__ bv,
    const float* __restrict__ Wqp, const float* __restrict__ bqp,
    const float* __restrict__ Wkp, const float* __restrict__ bkp,
    const float* __restrict__ Wvp, const float* __restrict__ bvp,
    const float* __restrict__ Wb,  const float* __restrict__ Wo,
    float* __restrict__ ws)
{
    int b = blockIdx.x, t = threadIdx.x;
    _Float16* sh  = (_Float16*)(ws + OFF_SH);
    _Float16* wct = (_Float16*)(ws + OFF_WCT);
    _Float16* wot = (_Float16*)(ws + OFF_WOT);
    _Float16* wbt = (_Float16*)(ws + OFF_WBT);
    float* bct = ws + OFF_BCT;

    if (b < 144) {                          // s -> f16 (36864 float4s)
        int id = b * 256 + t;
        float4 v = ((const float4*)s)[id];
        _Float16 r[4] = { (_Float16)v.x, (_Float16)v.y, (_Float16)v.z, (_Float16)v.w };
        *(uint2*)(sh + id * 4) = *(uint2*)r;
        return;
    }
    __shared__ float tile[64 * 65];
    if (b < 252) {                          // Wcat^T tiles (108)
        int ti = b - 144;
        int k0 = (ti % 6) * 64, n0 = (ti / 6) * 64;
        int cl = t & 63, rg = t >> 6;
        int ncat = n0 + cl;
        const float* W; int dout, col;
        if      (ncat < 192) { W = Wq;  dout = 192; col = ncat; }
        else if (ncat < 384) { W = Wk;  dout = 192; col = ncat - 192; }
        else if (ncat < 576) { W = Wv;  dout = 192; col = ncat - 384; }
        else if (ncat < 720) { W = Wqp; dout = 144; col = ncat - 576; }
        else if (ncat < 864) { W = Wkp; dout = 144; col = ncat - 720; }
        else                 { W = Wvp; dout = 288; col = ncat - 864; }
        #pragma unroll
        for (int u = 0; u < 16; u++) {
            int r = rg * 16 + u;
            tile[r * 65 + cl] = W[(size_t)(k0 + r) * dout + col];
        }
        __syncthreads();
        #pragma unroll
        for (int u2 = 0; u2 < 2; u2++) {
            int item = t + 256 * u2;
            int nl = item >> 3, kg = item & 7;
            half8 rr;
            #pragma unroll
            for (int jj = 0; jj < 8; jj++) rr[jj] = (_Float16)tile[(kg * 8 + jj) * 65 + nl];
            *(half8*)(wct + (size_t)(n0 + nl) * 384 + k0 + kg * 8) = rr;
        }
        return;
    }
    if (b < 450) {                          // Wo^T tiles (198)
        int ti = b - 252;
        int k0 = (ti % 33) * 64, n0 = (ti / 33) * 64;
        int cl = t & 63, rg = t >> 6;
        #pragma unroll
        for (int u = 0; u < 16; u++) {
            int r = rg * 16 + u;
            tile[r * 65 + cl] = Wo[(size_t)(k0 + r) * 384 + n0 + cl];
        }
        __syncthreads();
        #pragma unroll
        for (int u2 = 0; u2 < 2; u2++) {
            int item = t + 256 * u2;
            int nl = item >> 3, kg = item & 7;
            half8 rr;
            #pragma unroll
            for (int jj = 0; jj < 8; jj++) rr[jj] = (_Float16)tile[(kg * 8 + jj) * 65 + nl];
            *(half8*)(wot + (size_t)(n0 + nl) * 2112 + k0 + kg * 8) = rr;
        }
        return;
    }
    // b == 450: WbT + bcat
    for (int e = t; e < 2048; e += 256) {
        int h = e >> 7, c = e & 127;
        wbt[h * 128 + c] = (h < 12) ? (_Float16)(WLc * Wb[c * 12 + h]) : (_Float16)0.f;
    }
    for (int e = t; e < 1152; e += 256) {
        float bv_;
        if      (e < 192) bv_ = bq[e];
        else if (e < 384) bv_ = bk[e - 192];
        else if (e < 576) bv_ = bv[e - 384];
        else if (e < 720) bv_ = bqp[e - 576];
        else if (e < 864) bv_ = bkp[e - 720];
        else              bv_ = bvp[e - 864];
        bct[e] = bv_;
    }
}

// ---------------------------------------------------------------------------
// K1: proj MFMA (f16): P(384x1152) = s @ Wcat + bcat. grid (18,6) x 256
// ---------------------------------------------------------------------------
__global__ __launch_bounds__(256) void proj_mfma(float* __restrict__ ws)
{
    const _Float16* sh  = (const _Float16*)(ws + OFF_SH);
    const _Float16* wct = (const _Float16*)(ws + OFF_WCT);
    const float* bct = ws + OFF_BCT;
    float* P = ws + OFF_P;

    int t = threadIdx.x, w = t >> 6, lane = t & 63;
    int m = lane & 15, q = lane >> 4;
    int n0 = blockIdx.x * 64, m0 = blockIdx.y * 64 + w * 16;

    f32x4 acc[4] = {0};
    const _Float16* arow = sh + (size_t)(m0 + m) * 384;
    #pragma unroll 4
    for (int s = 0; s < 12; s++) {
        int k = s * 32 + q * 8;
        half8 a = *(const half8*)(arow + k);
        #pragma unroll
        for (int nt = 0; nt < 4; nt++) {
            half8 b = *(const half8*)(wct + (size_t)(n0 + nt * 16 + m) * 384 + k);
            acc[nt] = __builtin_amdgcn_mfma_f32_16x16x32_f16(a, b, acc[nt], 0, 0, 0);
        }
    }
    #pragma unroll
    for (int nt = 0; nt < 4; nt++) {
        int col = n0 + nt * 16 + m;
        float bias = bct[col];
        #pragma unroll
        for (int r = 0; r < 4; r++)
            P[(size_t)(m0 + q * 4 + r) * 1152 + col] = acc[nt][r] + bias;
    }
}

// ---------------------------------------------------------------------------
// K2: prep — per-i block. Qe[i][h*32+c] f32, Ke[h][i][32] f32, Ve_t f16
// ---------------------------------------------------------------------------
__global__ __launch_bounds__(192) void prep_kernel(
    const float* __restrict__ T, const float* __restrict__ hw,
    float* __restrict__ ws)
{
    int i = blockIdx.x, t = threadIdx.x;
    const float* pr = ws + OFF_P + (size_t)i * 1152;
    float* Qe = ws + OFF_QE;
    float* Ke = ws + OFF_KE;
    _Float16* vet = (_Float16*)(ws + OFF_VET);

    __shared__ float sT[16], sG[12];
    __shared__ float sTQ[12][4][3], sTK[12][4][3];
    if (t < 16) sT[t] = T[i * 16 + t];
    if (t < 12) { float x = hw[t]; sG[t] = (x > 20.f) ? x : log1pf(__expf(x)); }
    __syncthreads();
    float R00=sT[0],R01=sT[1],R02=sT[2],t0=sT[3];
    float R10=sT[4],R11=sT[5],R12=sT[6],t1=sT[7];
    float R20=sT[8],R21=sT[9],R22=sT[10],t2=sT[11];

    if (t < 48) {            // q-points
        int h = t >> 2, p = t & 3;
        float a0 = pr[576 + 0*48 + h*4 + p], a1 = pr[576 + 1*48 + h*4 + p], a2 = pr[576 + 2*48 + h*4 + p];
        sTQ[h][p][0] = R00*a0 + R01*a1 + R02*a2 + t0;
        sTQ[h][p][1] = R10*a0 + R11*a1 + R12*a2 + t1;
        sTQ[h][p][2] = R20*a0 + R21*a1 + R22*a2 + t2;
    } else if (t < 96) {     // k-points
        int tt = t - 48, h = tt >> 2, p = tt & 3;
        float a0 = pr[720 + 0*48 + h*4 + p], a1 = pr[720 + 1*48 + h*4 + p], a2 = pr[720 + 2*48 + h*4 + p];
        sTK[h][p][0] = R00*a0 + R01*a1 + R02*a2 + t0;
        sTK[h][p][1] = R10*a0 + R11*a1 + R12*a2 + t1;
        sTK[h][p][2] = R20*a0 + R21*a1 + R22*a2 + t2;
    } else {                 // v-points -> Ve_t
        int tt = t - 96, h = tt >> 3, p = tt & 7;
        float a0 = pr[864 + 0*96 + h*8 + p], a1 = pr[864 + 1*96 + h*8 + p], a2 = pr[864 + 2*96 + h*8 + p];
        vet[(size_t)(h*48 + 16 + p*3 + 0) * 384 + i] = (_Float16)(R00*a0 + R01*a1 + R02*a2 + t0);
        vet[(size_t)(h*48 + 16 + p*3 + 1) * 384 + i] = (_Float16)(R10*a0 + R11*a1 + R12*a2 + t1);
        vet[(size_t)(h*48 + 16 + p*3 + 2) * 384 + i] = (_Float16)(R20*a0 + R21*a1 + R22*a2 + t2);
    }
    {
        int h = t >> 4, c = t & 15;
        vet[(size_t)(h*48 + c) * 384 + i] = (_Float16)pr[384 + h*16 + c];
        if (t < 96) vet[(size_t)((t>>3)*48 + 40 + (t&7)) * 384 + i] = (_Float16)0.f;
        Qe[(size_t)i*384 + h*32 + c] = WLc * 0.25f * pr[h*16 + c];
        Ke[((size_t)h*384 + i)*32 + c] = pr[192 + h*16 + c];
    }
    __syncthreads();
    if (t < 144) {
        int h = t / 12, d = t % 12, p = d / 3, r = d % 3;
        float gw = WLc * sG[h] * WCc;
        Qe[(size_t)i*384 + h*32 + 16 + d] = gw * sTQ[h][p][r];
        Ke[((size_t)h*384 + i)*32 + 16 + d] = sTK[h][p][r];
    }
    if (t < 12) {
        int h = t;
        float sqq = 0.f, sqk = 0.f;
        #pragma unroll
        for (int p = 0; p < 4; p++)
            #pragma unroll
            for (int r = 0; r < 3; r++) { sqq += sTQ[h][p][r]*sTQ[h][p][r]; sqk += sTK[h][p][r]*sTK[h][p][r]; }
        float gw = WLc * sG[h] * WCc;
        Qe[(size_t)i*384 + h*32 + 28] = -0.5f * gw;
        Qe[(size_t)i*384 + h*32 + 29] = -0.5f * gw * sqq;
        Qe[(size_t)i*384 + h*32 + 30] = 0.f;
        Qe[(size_t)i*384 + h*32 + 31] = 0.f;
        Ke[((size_t)h*384 + i)*32 + 28] = sqk;
        Ke[((size_t)h*384 + i)*32 + 29] = 1.f;
        Ke[((size_t)h*384 + i)*32 + 30] = 0.f;
        Ke[((size_t)h*384 + i)*32 + 31] = 0.f;
    }
}

// ---------------------------------------------------------------------------
// K3: fused attention per residue i, 4 barriers total.
//  p1: bias MFMA, z direct-global A-fragments (24 m-tiles over j)
//  p2: logits fp32 (Qe LDS dot Ke L2) into same LDS slots
//  p3: full-row softmax (wave per 3 heads), att -> LDS + global
//  p4: pairwise MFMA, z direct-global B-fragments; write cat cols 576+
// ---------------------------------------------------------------------------
__global__ __launch_bounds__(256) void attn_fused(
    const float* __restrict__ z, const float* __restrict__ bb,
    float* __restrict__ ws)
{
    int i = blockIdx.x, t = threadIdx.x, w = t >> 6, lane = t & 63;
    int m16 = lane & 15, q = lane >> 4;

    __shared__ float sBias[384 * 13];        // bias then logits
    __shared__ _Float16 sAtt[16 * 392];
    __shared__ _Float16 wbl[16 * 136];
    __shared__ float sQe[384];
    __shared__ float sBB[12];

    const float* Qe = ws + OFF_QE;
    const float* Ke = ws + OFF_KE;
    const _Float16* wbt = (const _Float16*)(ws + OFF_WBT);
    _Float16* attg = (_Float16*)(ws + OFF_ATT);
    _Float16* crow = (_Float16*)(ws + OFF_CAT) + (size_t)i * 2112;
    const float* zrow = z + (size_t)i * 384 * 128;

    if (t < 12) sBB[t] = WLc * bb[t];
    {
        int row = t >> 4, c8 = (t & 15) * 8;
        *(half8*)(wbl + row * 136 + c8) = *(const half8*)(wbt + row * 128 + c8);
    }
    for (int e = t; e < 4 * 392; e += 256) sAtt[12 * 392 + e] = (_Float16)0.f;
    for (int e = t; e < 384; e += 256) sQe[e] = Qe[(size_t)i * 384 + e];
    __syncthreads();

    // p1: bias MFMA. m-tile mt = w + 4u; rows j = mt*16+m16; cols h = m16
    #pragma unroll
    for (int u = 0; u < 6; u++) {
        int j = (w + 4 * u) * 16 + m16;
        const float* zp = zrow + (size_t)j * 128 + q * 8;
        f32x4 acc = {0.f, 0.f, 0.f, 0.f};
        #pragma unroll
        for (int s = 0; s < 4; s++) {
            float4 v0 = *(const float4*)(zp + s * 32);
            float4 v1 = *(const float4*)(zp + s * 32 + 4);
            half8 a;
            a[0]=(_Float16)v0.x; a[1]=(_Float16)v0.y; a[2]=(_Float16)v0.z; a[3]=(_Float16)v0.w;
            a[4]=(_Float16)v1.x; a[5]=(_Float16)v1.y; a[6]=(_Float16)v1.z; a[7]=(_Float16)v1.w;
            half8 b = *(const half8*)(wbl + m16 * 136 + s * 32 + q * 8);
            acc = __builtin_amdgcn_mfma_f32_16x16x32_f16(a, b, acc, 0, 0, 0);
        }
        if (m16 < 12) {
            #pragma unroll
            for (int r = 0; r < 4; r++)
                sBias[((w + 4 * u) * 16 + q * 4 + r) * 13 + m16] = acc[r];
        }
    }
    __syncthreads();

    // p2: logits fp32
    for (int j = t; j < 384; j += 256) {
        #pragma unroll
        for (int h = 0; h < 12; h++) {
            const float4* k4 = (const float4*)(Ke + ((size_t)h * 384 + j) * 32);
            float dot = 0.f;
            #pragma unroll
            for (int uu = 0; uu < 8; uu++) {
                float4 kv = k4[uu];
                dot += sQe[h*32+uu*4+0]*kv.x + sQe[h*32+uu*4+1]*kv.y
                     + sQe[h*32+uu*4+2]*kv.z + sQe[h*32+uu*4+3]*kv.w;
            }
            sBias[j * 13 + h] = sBias[j * 13 + h] + sBB[h] + dot;
        }
    }
    __syncthreads();

    // p3: softmax; wave w -> heads 3w..3w+2
    #pragma unroll
    for (int u = 0; u < 3; u++) {
        int h = w * 3 + u;
        float v[6], mx = -1e30f;
        #pragma unroll
        for (int g = 0; g < 6; g++) { v[g] = sBias[(lane + 64*g) * 13 + h]; mx = fmaxf(mx, v[g]); }
        #pragma unroll
        for (int off = 1; off < 64; off <<= 1) mx = fmaxf(mx, __shfl_xor(mx, off));
        float sm = 0.f;
        #pragma unroll
        for (int g = 0; g < 6; g++) { v[g] = __expf(v[g] - mx); sm += v[g]; }
        #pragma unroll
        for (int off = 1; off < 64; off <<= 1) sm += __shfl_xor(sm, off);
        float inv = 1.0f / sm;
        #pragma unroll
        for (int g = 0; g < 6; g++) {
            _Float16 a = (_Float16)(v[g] * inv);
            sAtt[h * 392 + lane + 64 * g] = a;
            attg[((size_t)h * 384 + i) * 384 + lane + 64 * g] = a;
        }
    }
    __syncthreads();

    // p4: pairwise MFMA. A rows h = m16 (12-15 zero); B cols c = w*32+sub*16+m16
    f32x4 apw0 = {0}, apw1 = {0};
    #pragma unroll 3
    for (int s = 0; s < 12; s++) {
        int k = s * 32 + q * 8;
        half8 a = *(const half8*)(sAtt + m16 * 392 + k);
        const float* zp = zrow + (size_t)k * 128 + w * 32 + m16;
        half8 b0, b1;
        #pragma unroll
        for (int jj = 0; jj < 8; jj++) {
            b0[jj] = (_Float16)zp[(size_t)jj * 128];
            b1[jj] = (_Float16)zp[(size_t)jj * 128 + 16];
        }
        apw0 = __builtin_amdgcn_mfma_f32_16x16x32_f16(a, b0, apw0, 0, 0, 0);
        apw1 = __builtin_amdgcn_mfma_f32_16x16x32_f16(a, b1, apw1, 0, 0, 0);
    }
    if (q < 3) {
        #pragma unroll
        for (int r = 0; r < 4; r++) {
            int h = q * 4 + r;
            crow[576 + h * 128 + w * 32 + m16]      = (_Float16)apw0[r];
            crow[576 + h * 128 + w * 32 + 16 + m16] = (_Float16)apw1[r];
        }
    }
}

// ---------------------------------------------------------------------------
// K4: out40 MFMA + epilogue: att[h] @ VeT[h]^T, then v/pts/norm -> cat 0..575
// grid (12 i-tiles of 32, 12 h) x 128
// ---------------------------------------------------------------------------
__global__ __launch_bounds__(128) void out40_ep(
    const float* __restrict__ T, float* __restrict__ ws)
{
    const _Float16* attg = (const _Float16*)(ws + OFF_ATT);
    const _Float16* vet  = (const _Float16*)(ws + OFF_VET);
    _Float16* catb = (_Float16*)(ws + OFF_CAT);

    int h = blockIdx.y, t = threadIdx.x, w = t >> 6, lane = t & 63;
    int m16 = lane & 15, q = lane >> 4;
    int i0 = blockIdx.x * 32;

    __shared__ float sO[32 * 49];
    __shared__ float sTT[32 * 17];
    for (int e = t; e < 512; e += 128)
        sTT[(e >> 4) * 17 + (e & 15)] = T[(size_t)(i0 + (e >> 4)) * 16 + (e & 15)];

    f32x4 acc[3] = {0};
    const _Float16* arow = attg + ((size_t)h * 384 + i0 + w * 16 + m16) * 384;
    #pragma unroll 3
    for (int s = 0; s < 12; s++) {
        int k = s * 32 + q * 8;
        half8 a = *(const half8*)(arow + k);
        #pragma unroll
        for (int nt = 0; nt < 3; nt++) {
            half8 b = *(const half8*)(vet + (size_t)(h * 48 + nt * 16 + m16) * 384 + k);
            acc[nt] = __builtin_amdgcn_mfma_f32_16x16x32_f16(a, b, acc[nt], 0, 0, 0);
        }
    }
    #pragma unroll
    for (int nt = 0; nt < 3; nt++)
        #pragma unroll
        for (int r = 0; r < 4; r++)
            sO[(w * 16 + q * 4 + r) * 49 + nt * 16 + m16] = acc[nt][r];
    __syncthreads();

    for (int e = t; e < 512; e += 128) {     // v_out
        int il = e >> 4, c = e & 15;
        catb[(size_t)(i0 + il) * 2112 + h * 16 + c] = (_Float16)sO[il * 49 + c];
    }
    for (int e = t; e < 256; e += 128) {     // points + norm
        int il = e >> 3, p = e & 7;
        const float* o = sO + il * 49 + 16 + p * 3;
        const float* Ti = sTT + il * 17;
        float x0 = o[0] - Ti[3], x1 = o[1] - Ti[7], x2 = o[2] - Ti[11];
        float r0 = Ti[0]*x0 + Ti[4]*x1 + Ti[8]*x2;
        float r1 = Ti[1]*x0 + Ti[5]*x1 + Ti[9]*x2;
        float r2 = Ti[2]*x0 + Ti[6]*x1 + Ti[10]*x2;
        _Float16* cr = catb + (size_t)(i0 + il) * 2112;
        cr[192 + 0*96 + h*8 + p] = (_Float16)r0;
        cr[192 + 1*96 + h*8 + p] = (_Float16)r1;
        cr[192 + 2*96 + h*8 + p] = (_Float16)r2;
        cr[480 + h*8 + p] = (_Float16)sqrtf(r0*r0 + r1*r1 + r2*r2);
    }
}

// ---------------------------------------------------------------------------
// K5: out GEMM (f16): out = concat(384x2112) @ Wo + bo. grid (6,6) x 256
// ---------------------------------------------------------------------------
__global__ __launch_bounds__(256) void outgemm_mfma(
    const float* __restrict__ bo, float* __restrict__ ws, float* __restrict__ out)
{
    const _Float16* catb = (const _Float16*)(ws + OFF_CAT);
    const _Float16* wot  = (const _Float16*)(ws + OFF_WOT);

    int t = threadIdx.x, w = t >> 6, lane = t & 63;
    int m = lane & 15, q = lane >> 4;
    int n0 = blockIdx.x * 64, m0 = blockIdx.y * 64 + w * 16;

    f32x4 acc[4] = {0};
    const _Float16* arow = catb + (size_t)(m0 + m) * 2112;
    #pragma unroll 2
    for (int s = 0; s < 66; s++) {
        int k = s * 32 + q * 8;
        half8 a = *(const half8*)(arow + k);
        #pragma unroll
        for (int nt = 0; nt < 4; nt++) {
            half8 b = *(const half8*)(wot + (size_t)(n0 + nt * 16 + m) * 2112 + k);
            acc[nt] = __builtin_amdgcn_mfma_f32_16x16x32_f16(a, b, acc[nt], 0, 0, 0);
        }
    }
    #pragma unroll
    for (int nt = 0; nt < 4; nt++) {
        int col = n0 + nt * 16 + m;
        float bias = bo[col];
        #pragma unroll
        for (int r = 0; r < 4; r++)
            out[(size_t)(m0 + q * 4 + r) * 384 + col] = acc[nt][r] + bias;
    }
}

extern "C" void kernel_launch(void* const* d_in, const int* in_sizes, int n_in,
                              void* d_out, int out_size, void* d_ws, size_t ws_size,
                              hipStream_t stream)
{
    const float* s   = (const float*)d_in[0];
    const float* z   = (const float*)d_in[1];
    const float* T   = (const float*)d_in[2];
    const float* Wq  = (const float*)d_in[3];
    const float* bq  = (const float*)d_in[4];
    const float* Wk  = (const float*)d_in[5];
    const float* bk  = (const float*)d_in[6];
    const float* Wv  = (const float*)d_in[7];
    const float* bv  = (const float*)d_in[8];
    const float* Wqp = (const float*)d_in[9];
    const float* bqp = (const float*)d_in[10];
    const float* Wkp = (const float*)d_in[11];
    const float* bkp = (const float*)d_in[12];
    const float* Wvp = (const float*)d_in[13];
    const float* bvp = (const float*)d_in[14];
    const float* Wb  = (const float*)d_in[15];
    const float* bb  = (const float*)d_in[16];
    const float* Wo  = (const float*)d_in[17];
    const float* bo  = (const float*)d_in[18];
    const float* hw  = (const float*)d_in[19];
    float* ws  = (float*)d_ws;
    float* out = (float*)d_out;

    pack_kernel<<<451, 256, 0, stream>>>(s, Wq, bq, Wk, bk, Wv, bv,
                                         Wqp, bqp, Wkp, bkp, Wvp, bvp, Wb, Wo, ws);
    proj_mfma<<<dim3(18, 6), 256, 0, stream>>>(ws);
    prep_kernel<<<384, 192, 0, stream>>>(T, hw, ws);
    attn_fused<<<384, 256, 0, stream>>>(z, bb, ws);
    out40_ep<<<dim3(12, 12), 128, 0, stream>>>(T, ws);
    outgemm_mfma<<<dim3(6, 6), 256, 0, stream>>>(bo, ws, out);
}

// Round 5
// 212.030 us; speedup vs baseline: 1.3534x; 1.3534x over previous
//
#include <hip/hip_runtime.h>
#include <math.h>

#define NRES 384
#define NH   12
#define WLc 0.5773502691896258f
#define WCc 0.23570226039551587f

typedef __attribute__((ext_vector_type(8))) _Float16 half8;
typedef __attribute__((ext_vector_type(4))) float f32x4;

// workspace layout (float offsets), lifetime-overlaid:
#define OFF_P    0          // f32 [384][1152] proj out (dead after prep)
#define OFF_PW   0          // f32 [384][1536] pairwise acc (zeroed by bias_mfma, lives after prep)
#define OFF_SH   442368     // f16 [384][384] s (dead after proj)
#define OFF_WCT  516096     // f16 [1152][384] Wcat^T (dead after proj; PW overlaps first 73728 slots)
#define OFF_BCT  737280     // f32 [1152]
#define OFF_QE   738432     // f32 [384][384] (i, h*32+c)
#define OFF_KE   885888     // f32 [12][384][32]
#define OFF_VET  1033344    // f16 [12][48][384]
#define OFF_WOT  1143936    // f16 [384][2112] Wo^T
#define OFF_CAT  1549440    // f16 [384][576] concat cols 0..575
#define OFF_ATT  1660032    // f16 [12][384][384] att
#define OFF_BIAS 2544768    // f16 [12][384][384] wl*(z@Wb+bb)
// end 3429504 floats = 13.72 MB (<= proven 14.0 MB)

// ---------------------------------------------------------------------------
// K0: pack. s->f16; Wcat^T & Wo^T LDS-tiled transpose; bcat; out init w/ bo.
// grid 1027 x 256
// ---------------------------------------------------------------------------
__global__ __launch_bounds__(256) void pack_kernel(
    const float* __restrict__ s,
    const float* __restrict__ Wq,  const float* __restrict__ bq,
    const float* __restrict__ Wk,  const float* __restrict__ bk,
    const float* __restrict__ Wv,  const float* __restrict__ bv,
    const float* __restrict__ Wqp, const float* __restrict__ bqp,
    const float* __restrict__ Wkp, const float* __restrict__ bkp,
    const float* __restrict__ Wvp, const float* __restrict__ bvp,
    const float* __restrict__ Wo,  const float* __restrict__ bo,
    float* __restrict__ ws, float* __restrict__ out)
{
    int b = blockIdx.x, t = threadIdx.x;
    _Float16* sh  = (_Float16*)(ws + OFF_SH);
    _Float16* wct = (_Float16*)(ws + OFF_WCT);
    _Float16* wot = (_Float16*)(ws + OFF_WOT);
    float* bct = ws + OFF_BCT;

    if (b < 144) {                          // s -> f16
        int id = b * 256 + t;
        float4 v = ((const float4*)s)[id];
        _Float16 r[4] = { (_Float16)v.x, (_Float16)v.y, (_Float16)v.z, (_Float16)v.w };
        *(uint2*)(sh + id * 4) = *(uint2*)r;
        return;
    }
    __shared__ float tile[64 * 65];
    if (b < 252) {                          // Wcat^T tiles (108)
        int ti = b - 144;
        int k0 = (ti % 6) * 64, n0 = (ti / 6) * 64;
        int cl = t & 63, rg = t >> 6;
        int ncat = n0 + cl;
        const float* W; int dout, col;
        if      (ncat < 192) { W = Wq;  dout = 192; col = ncat; }
        else if (ncat < 384) { W = Wk;  dout = 192; col = ncat - 192; }
        else if (ncat < 576) { W = Wv;  dout = 192; col = ncat - 384; }
        else if (ncat < 720) { W = Wqp; dout = 144; col = ncat - 576; }
        else if (ncat < 864) { W = Wkp; dout = 144; col = ncat - 720; }
        else                 { W = Wvp; dout = 288; col = ncat - 864; }
        #pragma unroll
        for (int u = 0; u < 16; u++) {
            int r = rg * 16 + u;
            tile[r * 65 + cl] = W[(size_t)(k0 + r) * dout + col];
        }
        __syncthreads();
        #pragma unroll
        for (int u2 = 0; u2 < 2; u2++) {
            int item = t + 256 * u2;
            int nl = item >> 3, kg = item & 7;
            half8 rr;
            #pragma unroll
            for (int jj = 0; jj < 8; jj++) rr[jj] = (_Float16)tile[(kg * 8 + jj) * 65 + nl];
            *(half8*)(wct + (size_t)(n0 + nl) * 384 + k0 + kg * 8) = rr;
        }
        return;
    }
    if (b < 450) {                          // Wo^T tiles (198)
        int ti = b - 252;
        int k0 = (ti % 33) * 64, n0 = (ti / 33) * 64;
        int cl = t & 63, rg = t >> 6;
        #pragma unroll
        for (int u = 0; u < 16; u++) {
            int r = rg * 16 + u;
            tile[r * 65 + cl] = Wo[(size_t)(k0 + r) * 384 + n0 + cl];
        }
        __syncthreads();
        #pragma unroll
        for (int u2 = 0; u2 < 2; u2++) {
            int item = t + 256 * u2;
            int nl = item >> 3, kg = item & 7;
            half8 rr;
            #pragma unroll
            for (int jj = 0; jj < 8; jj++) rr[jj] = (_Float16)tile[(kg * 8 + jj) * 65 + nl];
            *(half8*)(wot + (size_t)(n0 + nl) * 2112 + k0 + kg * 8) = rr;
        }
        return;
    }
    if (b == 450) {                         // bcat
        for (int e = t; e < 1152; e += 256) {
            float bv_;
            if      (e < 192) bv_ = bq[e];
            else if (e < 384) bv_ = bk[e - 192];
            else if (e < 576) bv_ = bv[e - 384];
            else if (e < 720) bv_ = bqp[e - 576];
            else if (e < 864) bv_ = bkp[e - 720];
            else              bv_ = bvp[e - 864];
            bct[e] = bv_;
        }
        return;
    }
    {                                       // out init with bo (576 blocks)
        int idx = (b - 451) * 256 + t;
        out[idx] = bo[idx % 384];
    }
}

// ---------------------------------------------------------------------------
// K1: proj MFMA (f16): P(384x1152) = s @ Wcat + bcat. grid (18,6) x 256
// ---------------------------------------------------------------------------
__global__ __launch_bounds__(256) void proj_mfma(float* __restrict__ ws)
{
    const _Float16* sh  = (const _Float16*)(ws + OFF_SH);
    const _Float16* wct = (const _Float16*)(ws + OFF_WCT);
    const float* bct = ws + OFF_BCT;
    float* P = ws + OFF_P;

    int t = threadIdx.x, w = t >> 6, lane = t & 63;
    int m = lane & 15, q = lane >> 4;
    int n0 = blockIdx.x * 64, m0 = blockIdx.y * 64 + w * 16;

    f32x4 acc[4] = {0};
    const _Float16* arow = sh + (size_t)(m0 + m) * 384;
    #pragma unroll 4
    for (int s = 0; s < 12; s++) {
        int k = s * 32 + q * 8;
        half8 a = *(const half8*)(arow + k);
        #pragma unroll
        for (int nt = 0; nt < 4; nt++) {
            half8 b = *(const half8*)(wct + (size_t)(n0 + nt * 16 + m) * 384 + k);
            acc[nt] = __builtin_amdgcn_mfma_f32_16x16x32_f16(a, b, acc[nt], 0, 0, 0);
        }
    }
    #pragma unroll
    for (int nt = 0; nt < 4; nt++) {
        int col = n0 + nt * 16 + m;
        float bias = bct[col];
        #pragma unroll
        for (int r = 0; r < 4; r++)
            P[(size_t)(m0 + q * 4 + r) * 1152 + col] = acc[nt][r] + bias;
    }
}

// ---------------------------------------------------------------------------
// K2: prep — per-i block. Qe[i][h*32+c] f32, Ke[h][i][32] f32, Ve_t f16
// ---------------------------------------------------------------------------
__global__ __launch_bounds__(192) void prep_kernel(
    const float* __restrict__ T, const float* __restrict__ hw,
    float* __restrict__ ws)
{
    int i = blockIdx.x, t = threadIdx.x;
    const float* pr = ws + OFF_P + (size_t)i * 1152;
    float* Qe = ws + OFF_QE;
    float* Ke = ws + OFF_KE;
    _Float16* vet = (_Float16*)(ws + OFF_VET);

    __shared__ float sT[16], sG[12];
    __shared__ float sTQ[12][4][3], sTK[12][4][3];
    if (t < 16) sT[t] = T[i * 16 + t];
    if (t < 12) { float x = hw[t]; sG[t] = (x > 20.f) ? x : log1pf(__expf(x)); }
    __syncthreads();
    float R00=sT[0],R01=sT[1],R02=sT[2],t0=sT[3];
    float R10=sT[4],R11=sT[5],R12=sT[6],t1=sT[7];
    float R20=sT[8],R21=sT[9],R22=sT[10],t2=sT[11];

    if (t < 48) {
        int h = t >> 2, p = t & 3;
        float a0 = pr[576 + 0*48 + h*4 + p], a1 = pr[576 + 1*48 + h*4 + p], a2 = pr[576 + 2*48 + h*4 + p];
        sTQ[h][p][0] = R00*a0 + R01*a1 + R02*a2 + t0;
        sTQ[h][p][1] = R10*a0 + R11*a1 + R12*a2 + t1;
        sTQ[h][p][2] = R20*a0 + R21*a1 + R22*a2 + t2;
    } else if (t < 96) {
        int tt = t - 48, h = tt >> 2, p = tt & 3;
        float a0 = pr[720 + 0*48 + h*4 + p], a1 = pr[720 + 1*48 + h*4 + p], a2 = pr[720 + 2*48 + h*4 + p];
        sTK[h][p][0] = R00*a0 + R01*a1 + R02*a2 + t0;
        sTK[h][p][1] = R10*a0 + R11*a1 + R12*a2 + t1;
        sTK[h][p][2] = R20*a0 + R21*a1 + R22*a2 + t2;
    } else {
        int tt = t - 96, h = tt >> 3, p = tt & 7;
        float a0 = pr[864 + 0*96 + h*8 + p], a1 = pr[864 + 1*96 + h*8 + p], a2 = pr[864 + 2*96 + h*8 + p];
        vet[(size_t)(h*48 + 16 + p*3 + 0) * 384 + i] = (_Float16)(R00*a0 + R01*a1 + R02*a2 + t0);
        vet[(size_t)(h*48 + 16 + p*3 + 1) * 384 + i] = (_Float16)(R10*a0 + R11*a1 + R12*a2 + t1);
        vet[(size_t)(h*48 + 16 + p*3 + 2) * 384 + i] = (_Float16)(R20*a0 + R21*a1 + R22*a2 + t2);
    }
    {
        int h = t >> 4, c = t & 15;
        vet[(size_t)(h*48 + c) * 384 + i] = (_Float16)pr[384 + h*16 + c];
        if (t < 96) vet[(size_t)((t>>3)*48 + 40 + (t&7)) * 384 + i] = (_Float16)0.f;
        Qe[(size_t)i*384 + h*32 + c] = WLc * 0.25f * pr[h*16 + c];
        Ke[((size_t)h*384 + i)*32 + c] = pr[192 + h*16 + c];
    }
    __syncthreads();
    if (t < 144) {
        int h = t / 12, d = t % 12, p = d / 3, r = d % 3;
        float gw = WLc * sG[h] * WCc;
        Qe[(size_t)i*384 + h*32 + 16 + d] = gw * sTQ[h][p][r];
        Ke[((size_t)h*384 + i)*32 + 16 + d] = sTK[h][p][r];
    }
    if (t < 12) {
        int h = t;
        float sqq = 0.f, sqk = 0.f;
        #pragma unroll
        for (int p = 0; p < 4; p++)
            #pragma unroll
            for (int r = 0; r < 3; r++) { sqq += sTQ[h][p][r]*sTQ[h][p][r]; sqk += sTK[h][p][r]*sTK[h][p][r]; }
        float gw = WLc * sG[h] * WCc;
        Qe[(size_t)i*384 + h*32 + 28] = -0.5f * gw;
        Qe[(size_t)i*384 + h*32 + 29] = -0.5f * gw * sqq;
        Qe[(size_t)i*384 + h*32 + 30] = 0.f;
        Qe[(size_t)i*384 + h*32 + 31] = 0.f;
        Ke[((size_t)h*384 + i)*32 + 28] = sqk;
        Ke[((size_t)h*384 + i)*32 + 29] = 1.f;
        Ke[((size_t)h*384 + i)*32 + 30] = 0.f;
        Ke[((size_t)h*384 + i)*32 + 31] = 0.f;
    }
}

// ---------------------------------------------------------------------------
// K3: bias MFMA: bias_f16[h][ij] = f16(wl*(z@Wb + bb)), ij = i*384+j flat.
// 2304 blocks x 256. Blocks 0..575 also zero the PW accumulator.
// ---------------------------------------------------------------------------
__global__ __launch_bounds__(256) void bias_mfma(
    const float* __restrict__ z, const float* __restrict__ Wb,
    const float* __restrict__ bb, float* __restrict__ ws)
{
    __shared__ _Float16 zb[64 * 136];
    __shared__ _Float16 wbT[16 * 136];
    __shared__ float sbb[16];
    _Float16* biasb = (_Float16*)(ws + OFF_BIAS);
    int b = blockIdx.x, t = threadIdx.x;

    if (b < 576) {                         // zero PW (589824 f32 = 576*256 float4)
        ((float4*)(ws + OFF_PW))[b * 256 + t] = (float4){0.f, 0.f, 0.f, 0.f};
    }

    size_t m0 = (size_t)b * 64;
    {   // stage z tile 64x128 -> f16 LDS
        int r = t >> 2, co = (t & 3) * 32;
        const float* zr = z + (m0 + r) * 128 + co;
        #pragma unroll
        for (int u = 0; u < 4; u++) {
            float4 v0 = ((const float4*)zr)[u * 2 + 0];
            float4 v1 = ((const float4*)zr)[u * 2 + 1];
            half8 rr;
            rr[0]=(_Float16)v0.x; rr[1]=(_Float16)v0.y; rr[2]=(_Float16)v0.z; rr[3]=(_Float16)v0.w;
            rr[4]=(_Float16)v1.x; rr[5]=(_Float16)v1.y; rr[6]=(_Float16)v1.z; rr[7]=(_Float16)v1.w;
            *(half8*)(zb + r * 136 + co + u * 8) = rr;
        }
    }
    if (t < 128) {
        #pragma unroll
        for (int h = 0; h < 12; h++) wbT[h * 136 + t] = (_Float16)(WLc * Wb[t * 12 + h]);
        #pragma unroll
        for (int h = 12; h < 16; h++) wbT[h * 136 + t] = (_Float16)0.f;
    }
    if (t < 16) sbb[t] = (t < 12) ? WLc * bb[t] : 0.f;
    __syncthreads();

    int w = t >> 6, lane = t & 63;
    int m = lane & 15, q = lane >> 4;
    f32x4 acc = {0};
    #pragma unroll
    for (int s = 0; s < 4; s++) {
        int k = s * 32 + q * 8;
        half8 a = *(const half8*)(zb + (w * 16 + m) * 136 + k);
        half8 bfr = *(const half8*)(wbT + m * 136 + k);
        acc = __builtin_amdgcn_mfma_f32_16x16x32_f16(a, bfr, acc, 0, 0, 0);
    }
    if (m < 12) {
        #pragma unroll
        for (int r = 0; r < 4; r++) {
            size_t ri = m0 + w * 16 + q * 4 + r;
            biasb[(size_t)m * 147456 + ri] = (_Float16)(acc[r] + sbb[m]);
        }
    }
}

// ---------------------------------------------------------------------------
// K4: logits + softmax -> att f16 [h][i][j]. grid (48 i-tiles, 12 h) x 512
// ---------------------------------------------------------------------------
__global__ __launch_bounds__(512) void logits_kernel(float* __restrict__ ws)
{
    __shared__ float sQe[8 * 32];
    __shared__ float sLg[8][384];
    __shared__ float sMS[16];

    int h = blockIdx.y, i0 = blockIdx.x * 8;
    int t = threadIdx.x;
    const float* Qe = ws + OFF_QE;
    const float* Ke = ws + OFF_KE;
    const _Float16* biasb = (const _Float16*)(ws + OFF_BIAS);
    _Float16* attg = (_Float16*)(ws + OFF_ATT);

    if (t < 256)
        sQe[t] = Qe[(size_t)(i0 + (t >> 5)) * 384 + h * 32 + (t & 31)];
    __syncthreads();

    float lgv[8];
    if (t < 384) {
        int j = t;
        float ke[32];
        const float4* kr = (const float4*)(Ke + ((size_t)h * 384 + j) * 32);
        #pragma unroll
        for (int u = 0; u < 8; u++) { float4 v = kr[u]; ke[u*4]=v.x; ke[u*4+1]=v.y; ke[u*4+2]=v.z; ke[u*4+3]=v.w; }
        #pragma unroll
        for (int ii = 0; ii < 8; ii++) {
            float acc = (float)biasb[(size_t)h * 147456 + (size_t)(i0 + ii) * 384 + j];
            #pragma unroll
            for (int c = 0; c < 32; c++) acc += sQe[ii * 32 + c] * ke[c];
            lgv[ii] = acc;
            sLg[ii][j] = acc;
        }
    }
    __syncthreads();
    {
        int w = t >> 6, lane = t & 63;
        float vv[6], mx = -1e30f;
        #pragma unroll
        for (int u = 0; u < 6; u++) { vv[u] = sLg[w][lane + 64 * u]; mx = fmaxf(mx, vv[u]); }
        #pragma unroll
        for (int off = 1; off < 64; off <<= 1) mx = fmaxf(mx, __shfl_xor(mx, off));
        float sm = 0.f;
        #pragma unroll
        for (int u = 0; u < 6; u++) sm += __expf(vv[u] - mx);
        #pragma unroll
        for (int off = 1; off < 64; off <<= 1) sm += __shfl_xor(sm, off);
        if (lane == 0) { sMS[w] = mx; sMS[8 + w] = sm; }
    }
    __syncthreads();
    if (t < 384) {
        int j = t;
        #pragma unroll
        for (int ii = 0; ii < 8; ii++) {
            float a = __expf(lgv[ii] - sMS[ii]) * (1.0f / sMS[8 + ii]);
            attg[((size_t)h * 384 + i0 + ii) * 384 + j] = (_Float16)a;
        }
    }
}

// ---------------------------------------------------------------------------
// K5: pairwise MFMA, j-split: PW[i][h][c] += att[h][i][j0:j0+128] @ z[i][j0:,:]
// grid (384 i, 3 jc) x 256. z staged [c][j] f16 LDS (stride 136), atomicAdd out.
// ---------------------------------------------------------------------------
__global__ __launch_bounds__(256) void pairwise_mfma(
    const float* __restrict__ z, float* __restrict__ ws)
{
    __shared__ _Float16 ztT[128 * 136];   // [c][j]
    int i = blockIdx.x, jc = blockIdx.y, j0 = jc * 128;
    int t = threadIdx.x, w = t >> 6, lane = t & 63;
    int m16 = lane & 15, q = lane >> 4;
    const _Float16* attg = (const _Float16*)(ws + OFF_ATT);
    float* PW = ws + OFF_PW;

    {   // coalesced gather: thread (c = t&127, jg = t>>7) packs 8 j per write
        int c = t & 127, jg = t >> 7;
        const float* zbase = z + ((size_t)i * 384 + j0 + jg * 8) * 128 + c;
        #pragma unroll
        for (int jt = 0; jt < 8; jt++) {
            half8 r;
            #pragma unroll
            for (int u = 0; u < 8; u++)
                r[u] = (_Float16)zbase[(size_t)(jt * 16 + u) * 128];
            *(half8*)(ztT + c * 136 + jt * 16 + jg * 8) = r;
        }
    }
    __syncthreads();

    f32x4 acc0 = {0}, acc1 = {0};
    const _Float16* arow = attg + ((size_t)(m16 < 12 ? m16 : 0) * 384 + i) * 384 + j0;
    #pragma unroll
    for (int ks = 0; ks < 4; ks++) {
        int k = ks * 32 + q * 8;
        half8 a;
        if (m16 < 12) a = *(const half8*)(arow + k);
        else          a = (half8){0,0,0,0,0,0,0,0};
        half8 b0 = *(const half8*)(ztT + (w * 32 + m16) * 136 + k);
        half8 b1 = *(const half8*)(ztT + (w * 32 + 16 + m16) * 136 + k);
        acc0 = __builtin_amdgcn_mfma_f32_16x16x32_f16(a, b0, acc0, 0, 0, 0);
        acc1 = __builtin_amdgcn_mfma_f32_16x16x32_f16(a, b1, acc1, 0, 0, 0);
    }
    if (q < 3) {
        #pragma unroll
        for (int r = 0; r < 4; r++) {
            int h = q * 4 + r;
            atomicAdd(&PW[(size_t)i * 1536 + h * 128 + w * 32 + m16],      acc0[r]);
            atomicAdd(&PW[(size_t)i * 1536 + h * 128 + w * 32 + 16 + m16], acc1[r]);
        }
    }
}

// ---------------------------------------------------------------------------
// K6: out40 MFMA + epilogue -> cat cols 0..575. grid (12 i-tiles, 12 h) x 128
// ---------------------------------------------------------------------------
__global__ __launch_bounds__(128) void out40_ep(
    const float* __restrict__ T, float* __restrict__ ws)
{
    const _Float16* attg = (const _Float16*)(ws + OFF_ATT);
    const _Float16* vet  = (const _Float16*)(ws + OFF_VET);
    _Float16* catb = (_Float16*)(ws + OFF_CAT);

    int h = blockIdx.y, t = threadIdx.x, w = t >> 6, lane = t & 63;
    int m16 = lane & 15, q = lane >> 4;
    int i0 = blockIdx.x * 32;

    __shared__ float sO[32 * 49];
    __shared__ float sTT[32 * 17];
    for (int e = t; e < 512; e += 128)
        sTT[(e >> 4) * 17 + (e & 15)] = T[(size_t)(i0 + (e >> 4)) * 16 + (e & 15)];

    f32x4 acc[3] = {0};
    const _Float16* arow = attg + ((size_t)h * 384 + i0 + w * 16 + m16) * 384;
    #pragma unroll 3
    for (int s = 0; s < 12; s++) {
        int k = s * 32 + q * 8;
        half8 a = *(const half8*)(arow + k);
        #pragma unroll
        for (int nt = 0; nt < 3; nt++) {
            half8 b = *(const half8*)(vet + (size_t)(h * 48 + nt * 16 + m16) * 384 + k);
            acc[nt] = __builtin_amdgcn_mfma_f32_16x16x32_f16(a, b, acc[nt], 0, 0, 0);
        }
    }
    #pragma unroll
    for (int nt = 0; nt < 3; nt++)
        #pragma unroll
        for (int r = 0; r < 4; r++)
            sO[(w * 16 + q * 4 + r) * 49 + nt * 16 + m16] = acc[nt][r];
    __syncthreads();

    for (int e = t; e < 512; e += 128) {
        int il = e >> 4, c = e & 15;
        catb[(size_t)(i0 + il) * 576 + h * 16 + c] = (_Float16)sO[il * 49 + c];
    }
    for (int e = t; e < 256; e += 128) {
        int il = e >> 3, p = e & 7;
        const float* o = sO + il * 49 + 16 + p * 3;
        const float* Ti = sTT + il * 17;
        float x0 = o[0] - Ti[3], x1 = o[1] - Ti[7], x2 = o[2] - Ti[11];
        float r0 = Ti[0]*x0 + Ti[4]*x1 + Ti[8]*x2;
        float r1 = Ti[1]*x0 + Ti[5]*x1 + Ti[9]*x2;
        float r2 = Ti[2]*x0 + Ti[6]*x1 + Ti[10]*x2;
        _Float16* cr = catb + (size_t)(i0 + il) * 576;
        cr[192 + 0*96 + h*8 + p] = (_Float16)r0;
        cr[192 + 1*96 + h*8 + p] = (_Float16)r1;
        cr[192 + 2*96 + h*8 + p] = (_Float16)r2;
        cr[480 + h*8 + p] = (_Float16)sqrtf(r0*r0 + r1*r1 + r2*r2);
    }
}

// ---------------------------------------------------------------------------
// K7: out GEMM: out += concat @ Wo. A from CAT f16 (k<576) or PW f32 (k>=576).
// grid (6 nt, 12 mt, 6 kz) x 128, k-split 352, atomicAdd (out preset to bo).
// ---------------------------------------------------------------------------
__global__ __launch_bounds__(128) void outgemm_mfma(float* __restrict__ ws, float* __restrict__ out)
{
    const _Float16* catb = (const _Float16*)(ws + OFF_CAT);
    const float* PW = ws + OFF_PW;
    const _Float16* wot = (const _Float16*)(ws + OFF_WOT);

    int t = threadIdx.x, w = t >> 6, lane = t & 63;
    int m = lane & 15, q = lane >> 4;
    int n0 = blockIdx.x * 64;
    int m0 = blockIdx.y * 32 + w * 16;
    int kbase = blockIdx.z * 352;

    f32x4 acc[4] = {0};
    int row = m0 + m;
    #pragma unroll 2
    for (int s = 0; s < 11; s++) {
        int kb = kbase + s * 32;
        int k = kb + q * 8;
        half8 a;
        if (kb < 576) {
            a = *(const half8*)(catb + (size_t)row * 576 + k);
        } else {
            const float* pwp = PW + (size_t)row * 1536 + (k - 576);
            float4 u0 = ((const float4*)pwp)[0];
            float4 u1 = ((const float4*)pwp)[1];
            a[0]=(_Float16)u0.x; a[1]=(_Float16)u0.y; a[2]=(_Float16)u0.z; a[3]=(_Float16)u0.w;
            a[4]=(_Float16)u1.x; a[5]=(_Float16)u1.y; a[6]=(_Float16)u1.z; a[7]=(_Float16)u1.w;
        }
        #pragma unroll
        for (int nt = 0; nt < 4; nt++) {
            half8 b = *(const half8*)(wot + (size_t)(n0 + nt * 16 + m) * 2112 + k);
            acc[nt] = __builtin_amdgcn_mfma_f32_16x16x32_f16(a, b, acc[nt], 0, 0, 0);
        }
    }
    #pragma unroll
    for (int nt = 0; nt < 4; nt++) {
        int col = n0 + nt * 16 + m;
        #pragma unroll
        for (int r = 0; r < 4; r++)
            atomicAdd(&out[(size_t)(m0 + q * 4 + r) * 384 + col], acc[nt][r]);
    }
}

extern "C" void kernel_launch(void* const* d_in, const int* in_sizes, int n_in,
                              void* d_out, int out_size, void* d_ws, size_t ws_size,
                              hipStream_t stream)
{
    const float* s   = (const float*)d_in[0];
    const float* z   = (const float*)d_in[1];
    const float* T   = (const float*)d_in[2];
    const float* Wq  = (const float*)d_in[3];
    const float* bq  = (const float*)d_in[4];
    const float* Wk  = (const float*)d_in[5];
    const float* bk  = (const float*)d_in[6];
    const float* Wv  = (const float*)d_in[7];
    const float* bv  = (const float*)d_in[8];
    const float* Wqp = (const float*)d_in[9];
    const float* bqp = (const float*)d_in[10];
    const float* Wkp = (const float*)d_in[11];
    const float* bkp = (const float*)d_in[12];
    const float* Wvp = (const float*)d_in[13];
    const float* bvp = (const float*)d_in[14];
    const float* Wb  = (const float*)d_in[15];
    const float* bb  = (const float*)d_in[16];
    const float* Wo  = (const float*)d_in[17];
    const float* bo  = (const float*)d_in[18];
    const float* hw  = (const float*)d_in[19];
    float* ws  = (float*)d_ws;
    float* out = (float*)d_out;

    pack_kernel<<<1027, 256, 0, stream>>>(s, Wq, bq, Wk, bk, Wv, bv,
                                          Wqp, bqp, Wkp, bkp, Wvp, bvp, Wo, bo, ws, out);
    proj_mfma<<<dim3(18, 6), 256, 0, stream>>>(ws);
    prep_kernel<<<384, 192, 0, stream>>>(T, hw, ws);
    bias_mfma<<<2304, 256, 0, stream>>>(z, Wb, bb, ws);
    logits_kernel<<<dim3(48, 12), 512, 0, stream>>>(ws);
    pairwise_mfma<<<dim3(384, 3), 256, 0, stream>>>(z, ws);
    out40_ep<<<dim3(12, 12), 128, 0, stream>>>(T, ws);
    outgemm_mfma<<<dim3(6, 12, 6), 128, 0, stream>>>(ws, out);
}

// Round 6
// 203.285 us; speedup vs baseline: 1.4116x; 1.0430x over previous
//
#include <hip/hip_runtime.h>
#include <math.h>

#define NRES 384
#define NH   12
#define WLc 0.5773502691896258f
#define WCc 0.23570226039551587f

typedef __attribute__((ext_vector_type(8))) _Float16 half8;
typedef __attribute__((ext_vector_type(4))) float f32x4;

// workspace layout (float offsets), lifetime-overlaid:
#define OFF_P    0          // f32 [384][1152] proj out (dead after prep)
#define OFF_PW   0          // f32 [384][1536] pairwise acc (zeroed in logits_out40, used after)
#define OFF_SH   442368     // f16 [384][384] s (dead after proj)
#define OFF_WCT  516096     // f16 [1152][384] Wcat^T (dead after proj)
#define OFF_BCT  737280     // f32 [1152]
#define OFF_QE   738432     // f32 [384][384] (i, h*32+c)
#define OFF_KE   885888     // f32 [12][384][32]
#define OFF_VET  1033344    // f16 [12][48][384]
#define OFF_WOT  1143936    // f16 [384][2112] Wo^T
#define OFF_CAT  1549440    // f16 [384][576] concat cols 0..575
#define OFF_ATT  1660032    // f16 [12][384][384] att
#define OFF_BIAS 2544768    // f16 [12][384][384] wl*(z@Wb+bb)
// end 3429504 floats = 13.72 MB

// ---------------------------------------------------------------------------
// K0: pack + bias. Blocks 0..450: s->f16, Wcat^T, Wo^T, bcat.
// Blocks 451..2754: bias MFMA with direct-global z A-fragments.
// ---------------------------------------------------------------------------
__global__ __launch_bounds__(256) void pack_bias(
    const float* __restrict__ s,  const float* __restrict__ z,
    const float* __restrict__ Wq,  const float* __restrict__ bq,
    const float* __restrict__ Wk,  const float* __restrict__ bk,
    const float* __restrict__ Wv,  const float* __restrict__ bv,
    const float* __restrict__ Wqp, const float* __restrict__ bqp,
    const float* __restrict__ Wkp, const float* __restrict__ bkp,
    const float* __restrict__ Wvp, const float* __restrict__ bvp,
    const float* __restrict__ Wb,  const float* __restrict__ bb,
    const float* __restrict__ Wo,
    float* __restrict__ ws)
{
    int b = blockIdx.x, t = threadIdx.x;
    __shared__ float tile[64 * 65];
    __shared__ _Float16 wbT[16 * 136];
    __shared__ float sbb[16];

    if (b >= 451) {                         // ---- bias MFMA (2304 blocks) ----
        _Float16* biasb = (_Float16*)(ws + OFF_BIAS);
        int bi = b - 451;
        size_t m0 = (size_t)bi * 64;
        if (t < 128) {
            #pragma unroll
            for (int h = 0; h < 12; h++) wbT[h * 136 + t] = (_Float16)(WLc * Wb[t * 12 + h]);
            #pragma unroll
            for (int h = 12; h < 16; h++) wbT[h * 136 + t] = (_Float16)0.f;
        }
        if (t < 16) sbb[t] = (t < 12) ? WLc * bb[t] : 0.f;
        __syncthreads();
        int w = t >> 6, lane = t & 63;
        int m = lane & 15, q = lane >> 4;
        size_t ri = m0 + w * 16 + m;
        const float* zr = z + ri * 128 + q * 8;
        f32x4 acc = {0};
        #pragma unroll
        for (int sI = 0; sI < 4; sI++) {
            float4 v0 = *(const float4*)(zr + sI * 32);
            float4 v1 = *(const float4*)(zr + sI * 32 + 4);
            half8 a;
            a[0]=(_Float16)v0.x; a[1]=(_Float16)v0.y; a[2]=(_Float16)v0.z; a[3]=(_Float16)v0.w;
            a[4]=(_Float16)v1.x; a[5]=(_Float16)v1.y; a[6]=(_Float16)v1.z; a[7]=(_Float16)v1.w;
            half8 bf = *(const half8*)(wbT + m * 136 + sI * 32 + q * 8);
            acc = __builtin_amdgcn_mfma_f32_16x16x32_f16(a, bf, acc, 0, 0, 0);
        }
        if (m < 12) {
            #pragma unroll
            for (int r = 0; r < 4; r++)
                biasb[(size_t)m * 147456 + m0 + w * 16 + q * 4 + r] = (_Float16)(acc[r] + sbb[m]);
        }
        return;
    }

    _Float16* sh  = (_Float16*)(ws + OFF_SH);
    _Float16* wct = (_Float16*)(ws + OFF_WCT);
    _Float16* wot = (_Float16*)(ws + OFF_WOT);
    float* bct = ws + OFF_BCT;

    if (b < 144) {                          // s -> f16
        int id = b * 256 + t;
        float4 v = ((const float4*)s)[id];
        _Float16 r[4] = { (_Float16)v.x, (_Float16)v.y, (_Float16)v.z, (_Float16)v.w };
        *(uint2*)(sh + id * 4) = *(uint2*)r;
        return;
    }
    if (b < 252) {                          // Wcat^T tiles (108)
        int ti = b - 144;
        int k0 = (ti % 6) * 64, n0 = (ti / 6) * 64;
        int cl = t & 63, rg = t >> 6;
        int ncat = n0 + cl;
        const float* W; int dout, col;
        if      (ncat < 192) { W = Wq;  dout = 192; col = ncat; }
        else if (ncat < 384) { W = Wk;  dout = 192; col = ncat - 192; }
        else if (ncat < 576) { W = Wv;  dout = 192; col = ncat - 384; }
        else if (ncat < 720) { W = Wqp; dout = 144; col = ncat - 576; }
        else if (ncat < 864) { W = Wkp; dout = 144; col = ncat - 720; }
        else                 { W = Wvp; dout = 288; col = ncat - 864; }
        #pragma unroll
        for (int u = 0; u < 16; u++) {
            int r = rg * 16 + u;
            tile[r * 65 + cl] = W[(size_t)(k0 + r) * dout + col];
        }
        __syncthreads();
        #pragma unroll
        for (int u2 = 0; u2 < 2; u2++) {
            int item = t + 256 * u2;
            int nl = item >> 3, kg = item & 7;
            half8 rr;
            #pragma unroll
            for (int jj = 0; jj < 8; jj++) rr[jj] = (_Float16)tile[(kg * 8 + jj) * 65 + nl];
            *(half8*)(wct + (size_t)(n0 + nl) * 384 + k0 + kg * 8) = rr;
        }
        return;
    }
    if (b < 450) {                          // Wo^T tiles (198)
        int ti = b - 252;
        int k0 = (ti % 33) * 64, n0 = (ti / 33) * 64;
        int cl = t & 63, rg = t >> 6;
        #pragma unroll
        for (int u = 0; u < 16; u++) {
            int r = rg * 16 + u;
            tile[r * 65 + cl] = Wo[(size_t)(k0 + r) * 384 + n0 + cl];
        }
        __syncthreads();
        #pragma unroll
        for (int u2 = 0; u2 < 2; u2++) {
            int item = t + 256 * u2;
            int nl = item >> 3, kg = item & 7;
            half8 rr;
            #pragma unroll
            for (int jj = 0; jj < 8; jj++) rr[jj] = (_Float16)tile[(kg * 8 + jj) * 65 + nl];
            *(half8*)(wot + (size_t)(n0 + nl) * 2112 + k0 + kg * 8) = rr;
        }
        return;
    }
    // b == 450: bcat
    for (int e = t; e < 1152; e += 256) {
        float bv_;
        if      (e < 192) bv_ = bq[e];
        else if (e < 384) bv_ = bk[e - 192];
        else if (e < 576) bv_ = bv[e - 384];
        else if (e < 720) bv_ = bqp[e - 576];
        else if (e < 864) bv_ = bkp[e - 720];
        else              bv_ = bvp[e - 864];
        bct[e] = bv_;
    }
}

// ---------------------------------------------------------------------------
// K1: proj MFMA (f16): P(384x1152) = s @ Wcat + bcat. grid (18,12) x 128
// ---------------------------------------------------------------------------
__global__ __launch_bounds__(128) void proj_mfma(float* __restrict__ ws)
{
    const _Float16* sh  = (const _Float16*)(ws + OFF_SH);
    const _Float16* wct = (const _Float16*)(ws + OFF_WCT);
    const float* bct = ws + OFF_BCT;
    float* P = ws + OFF_P;

    int t = threadIdx.x, w = t >> 6, lane = t & 63;
    int m = lane & 15, q = lane >> 4;
    int n0 = blockIdx.x * 64, m0 = blockIdx.y * 32 + w * 16;

    f32x4 acc[4] = {0};
    const _Float16* arow = sh + (size_t)(m0 + m) * 384;
    #pragma unroll 4
    for (int s = 0; s < 12; s++) {
        int k = s * 32 + q * 8;
        half8 a = *(const half8*)(arow + k);
        #pragma unroll
        for (int nt = 0; nt < 4; nt++) {
            half8 b = *(const half8*)(wct + (size_t)(n0 + nt * 16 + m) * 384 + k);
            acc[nt] = __builtin_amdgcn_mfma_f32_16x16x32_f16(a, b, acc[nt], 0, 0, 0);
        }
    }
    #pragma unroll
    for (int nt = 0; nt < 4; nt++) {
        int col = n0 + nt * 16 + m;
        float bias = bct[col];
        #pragma unroll
        for (int r = 0; r < 4; r++)
            P[(size_t)(m0 + q * 4 + r) * 1152 + col] = acc[nt][r] + bias;
    }
}

// ---------------------------------------------------------------------------
// K2: prep — per-i block. Qe[i][h*32+c] f32, Ke[h][i][32] f32, Ve_t f16
// ---------------------------------------------------------------------------
__global__ __launch_bounds__(192) void prep_kernel(
    const float* __restrict__ T, const float* __restrict__ hw,
    float* __restrict__ ws)
{
    int i = blockIdx.x, t = threadIdx.x;
    const float* pr = ws + OFF_P + (size_t)i * 1152;
    float* Qe = ws + OFF_QE;
    float* Ke = ws + OFF_KE;
    _Float16* vet = (_Float16*)(ws + OFF_VET);

    __shared__ float sT[16], sG[12];
    __shared__ float sTQ[12][4][3], sTK[12][4][3];
    if (t < 16) sT[t] = T[i * 16 + t];
    if (t < 12) { float x = hw[t]; sG[t] = (x > 20.f) ? x : log1pf(__expf(x)); }
    __syncthreads();
    float R00=sT[0],R01=sT[1],R02=sT[2],t0=sT[3];
    float R10=sT[4],R11=sT[5],R12=sT[6],t1=sT[7];
    float R20=sT[8],R21=sT[9],R22=sT[10],t2=sT[11];

    if (t < 48) {
        int h = t >> 2, p = t & 3;
        float a0 = pr[576 + 0*48 + h*4 + p], a1 = pr[576 + 1*48 + h*4 + p], a2 = pr[576 + 2*48 + h*4 + p];
        sTQ[h][p][0] = R00*a0 + R01*a1 + R02*a2 + t0;
        sTQ[h][p][1] = R10*a0 + R11*a1 + R12*a2 + t1;
        sTQ[h][p][2] = R20*a0 + R21*a1 + R22*a2 + t2;
    } else if (t < 96) {
        int tt = t - 48, h = tt >> 2, p = tt & 3;
        float a0 = pr[720 + 0*48 + h*4 + p], a1 = pr[720 + 1*48 + h*4 + p], a2 = pr[720 + 2*48 + h*4 + p];
        sTK[h][p][0] = R00*a0 + R01*a1 + R02*a2 + t0;
        sTK[h][p][1] = R10*a0 + R11*a1 + R12*a2 + t1;
        sTK[h][p][2] = R20*a0 + R21*a1 + R22*a2 + t2;
    } else {
        int tt = t - 96, h = tt >> 3, p = tt & 7;
        float a0 = pr[864 + 0*96 + h*8 + p], a1 = pr[864 + 1*96 + h*8 + p], a2 = pr[864 + 2*96 + h*8 + p];
        vet[(size_t)(h*48 + 16 + p*3 + 0) * 384 + i] = (_Float16)(R00*a0 + R01*a1 + R02*a2 + t0);
        vet[(size_t)(h*48 + 16 + p*3 + 1) * 384 + i] = (_Float16)(R10*a0 + R11*a1 + R12*a2 + t1);
        vet[(size_t)(h*48 + 16 + p*3 + 2) * 384 + i] = (_Float16)(R20*a0 + R21*a1 + R22*a2 + t2);
    }
    {
        int h = t >> 4, c = t & 15;
        vet[(size_t)(h*48 + c) * 384 + i] = (_Float16)pr[384 + h*16 + c];
        if (t < 96) vet[(size_t)((t>>3)*48 + 40 + (t&7)) * 384 + i] = (_Float16)0.f;
        Qe[(size_t)i*384 + h*32 + c] = WLc * 0.25f * pr[h*16 + c];
        Ke[((size_t)h*384 + i)*32 + c] = pr[192 + h*16 + c];
    }
    __syncthreads();
    if (t < 144) {
        int h = t / 12, d = t % 12, p = d / 3, r = d % 3;
        float gw = WLc * sG[h] * WCc;
        Qe[(size_t)i*384 + h*32 + 16 + d] = gw * sTQ[h][p][r];
        Ke[((size_t)h*384 + i)*32 + 16 + d] = sTK[h][p][r];
    }
    if (t < 12) {
        int h = t;
        float sqq = 0.f, sqk = 0.f;
        #pragma unroll
        for (int p = 0; p < 4; p++)
            #pragma unroll
            for (int r = 0; r < 3; r++) { sqq += sTQ[h][p][r]*sTQ[h][p][r]; sqk += sTK[h][p][r]*sTK[h][p][r]; }
        float gw = WLc * sG[h] * WCc;
        Qe[(size_t)i*384 + h*32 + 28] = -0.5f * gw;
        Qe[(size_t)i*384 + h*32 + 29] = -0.5f * gw * sqq;
        Qe[(size_t)i*384 + h*32 + 30] = 0.f;
        Qe[(size_t)i*384 + h*32 + 31] = 0.f;
        Ke[((size_t)h*384 + i)*32 + 28] = sqk;
        Ke[((size_t)h*384 + i)*32 + 29] = 1.f;
        Ke[((size_t)h*384 + i)*32 + 30] = 0.f;
        Ke[((size_t)h*384 + i)*32 + 31] = 0.f;
    }
}

// ---------------------------------------------------------------------------
// K3: logits + softmax + out40 + epilogue. grid (48 i-tiles, 12 h) x 512.
// Also: PW zeroing and out-init (576 blocks exactly cover both).
// ---------------------------------------------------------------------------
__global__ __launch_bounds__(512) void logits_out40(
    const float* __restrict__ T, const float* __restrict__ bo,
    float* __restrict__ ws, float* __restrict__ out)
{
    __shared__ float sQe[8 * 32];
    __shared__ float sLg[8][384];
    __shared__ float sMS[16];
    __shared__ _Float16 sAttL[8 * 392];
    __shared__ float sO[8 * 49];
    __shared__ float sT8[8 * 16];

    int h = blockIdx.y, i0 = blockIdx.x * 8;
    int t = threadIdx.x;
    const float* Qe = ws + OFF_QE;
    const float* Ke = ws + OFF_KE;
    const _Float16* biasb = (const _Float16*)(ws + OFF_BIAS);
    const _Float16* vet = (const _Float16*)(ws + OFF_VET);
    _Float16* attg = (_Float16*)(ws + OFF_ATT);
    _Float16* catb = (_Float16*)(ws + OFF_CAT);

    {   // chores: out init + PW zero (bid 0..575, each 256 items)
        int bid = blockIdx.y * 48 + blockIdx.x;
        if (t < 256) {
            int e = bid * 256 + t;
            out[e] = bo[e % 384];
            ((float4*)(ws + OFF_PW))[e] = (float4){0.f, 0.f, 0.f, 0.f};
        }
    }
    if (t < 256)
        sQe[t] = Qe[(size_t)(i0 + (t >> 5)) * 384 + h * 32 + (t & 31)];
    if (t < 128)
        sT8[t] = T[(size_t)(i0 + (t >> 4)) * 16 + (t & 15)];
    __syncthreads();

    float lgv[8];
    if (t < 384) {
        int j = t;
        float ke[32];
        const float4* kr = (const float4*)(Ke + ((size_t)h * 384 + j) * 32);
        #pragma unroll
        for (int u = 0; u < 8; u++) { float4 v = kr[u]; ke[u*4]=v.x; ke[u*4+1]=v.y; ke[u*4+2]=v.z; ke[u*4+3]=v.w; }
        #pragma unroll
        for (int ii = 0; ii < 8; ii++) {
            float acc = (float)biasb[(size_t)h * 147456 + (size_t)(i0 + ii) * 384 + j];
            #pragma unroll
            for (int c = 0; c < 32; c++) acc += sQe[ii * 32 + c] * ke[c];
            lgv[ii] = acc;
            sLg[ii][j] = acc;
        }
    }
    __syncthreads();
    {
        int w = t >> 6, lane = t & 63;
        float vv[6], mx = -1e30f;
        #pragma unroll
        for (int u = 0; u < 6; u++) { vv[u] = sLg[w][lane + 64 * u]; mx = fmaxf(mx, vv[u]); }
        #pragma unroll
        for (int off = 1; off < 64; off <<= 1) mx = fmaxf(mx, __shfl_xor(mx, off));
        float sm = 0.f;
        #pragma unroll
        for (int u = 0; u < 6; u++) sm += __expf(vv[u] - mx);
        #pragma unroll
        for (int off = 1; off < 64; off <<= 1) sm += __shfl_xor(sm, off);
        if (lane == 0) { sMS[w] = mx; sMS[8 + w] = sm; }
    }
    __syncthreads();
    if (t < 384) {
        int j = t;
        #pragma unroll
        for (int ii = 0; ii < 8; ii++) {
            float a = __expf(lgv[ii] - sMS[ii]) * (1.0f / sMS[8 + ii]);
            attg[((size_t)h * 384 + i0 + ii) * 384 + j] = (_Float16)a;
            sAttL[ii * 392 + j] = (_Float16)a;
        }
    }
    __syncthreads();

    // out40 GEMM: waves 0..2 each take one 16-wide n-tile of Ve (48 cols)
    int w = t >> 6, lane = t & 63;
    int m16 = lane & 15, q = lane >> 4;
    if (w < 3) {
        int nt = w;
        f32x4 acc = {0};
        #pragma unroll 3
        for (int s = 0; s < 12; s++) {
            int k = s * 32 + q * 8;
            half8 a;
            if (m16 < 8) a = *(const half8*)(sAttL + m16 * 392 + k);
            else         a = (half8){0,0,0,0,0,0,0,0};
            half8 bfr = *(const half8*)(vet + (size_t)(h * 48 + nt * 16 + m16) * 384 + k);
            acc = __builtin_amdgcn_mfma_f32_16x16x32_f16(a, bfr, acc, 0, 0, 0);
        }
        #pragma unroll
        for (int r = 0; r < 4; r++) {
            int row = q * 4 + r;
            if (row < 8) sO[row * 49 + nt * 16 + m16] = acc[r];
        }
    }
    __syncthreads();

    if (t < 128) {   // v_out -> cat cols h*16..h*16+15
        int il = t >> 4, c = t & 15;
        catb[(size_t)(i0 + il) * 576 + h * 16 + c] = (_Float16)sO[il * 49 + c];
    }
    if (t < 64) {    // points + norm
        int il = t >> 3, p = t & 7;
        const float* o = sO + il * 49 + 16 + p * 3;
        const float* Ti = sT8 + il * 16;
        float x0 = o[0] - Ti[3], x1 = o[1] - Ti[7], x2 = o[2] - Ti[11];
        float r0 = Ti[0]*x0 + Ti[4]*x1 + Ti[8]*x2;
        float r1 = Ti[1]*x0 + Ti[5]*x1 + Ti[9]*x2;
        float r2 = Ti[2]*x0 + Ti[6]*x1 + Ti[10]*x2;
        _Float16* cr = catb + (size_t)(i0 + il) * 576;
        cr[192 + 0*96 + h*8 + p] = (_Float16)r0;
        cr[192 + 1*96 + h*8 + p] = (_Float16)r1;
        cr[192 + 2*96 + h*8 + p] = (_Float16)r2;
        cr[480 + h*8 + p] = (_Float16)sqrtf(r0*r0 + r1*r1 + r2*r2);
    }
}

// ---------------------------------------------------------------------------
// K4: pairwise MFMA, j-split: PW[i][h][c] += att[h][i][j0:] @ z[i][j0:,:]
// grid (384 i, 3 jc) x 256. z staged [c][j] f16 LDS, atomicAdd out.
// ---------------------------------------------------------------------------
__global__ __launch_bounds__(256) void pairwise_mfma(
    const float* __restrict__ z, float* __restrict__ ws)
{
    __shared__ _Float16 ztT[128 * 136];   // [c][j]
    int i = blockIdx.x, jc = blockIdx.y, j0 = jc * 128;
    int t = threadIdx.x, w = t >> 6, lane = t & 63;
    int m16 = lane & 15, q = lane >> 4;
    const _Float16* attg = (const _Float16*)(ws + OFF_ATT);
    float* PW = ws + OFF_PW;

    {   // coalesced gather
        int c = t & 127, jg = t >> 7;
        const float* zbase = z + ((size_t)i * 384 + j0 + jg * 8) * 128 + c;
        #pragma unroll
        for (int jt = 0; jt < 8; jt++) {
            half8 r;
            #pragma unroll
            for (int u = 0; u < 8; u++)
                r[u] = (_Float16)zbase[(size_t)(jt * 16 + u) * 128];
            *(half8*)(ztT + c * 136 + jt * 16 + jg * 8) = r;
        }
    }
    __syncthreads();

    f32x4 acc0 = {0}, acc1 = {0};
    const _Float16* arow = attg + ((size_t)(m16 < 12 ? m16 : 0) * 384 + i) * 384 + j0;
    #pragma unroll
    for (int ks = 0; ks < 4; ks++) {
        int k = ks * 32 + q * 8;
        half8 a;
        if (m16 < 12) a = *(const half8*)(arow + k);
        else          a = (half8){0,0,0,0,0,0,0,0};
        half8 b0 = *(const half8*)(ztT + (w * 32 + m16) * 136 + k);
        half8 b1 = *(const half8*)(ztT + (w * 32 + 16 + m16) * 136 + k);
        acc0 = __builtin_amdgcn_mfma_f32_16x16x32_f16(a, b0, acc0, 0, 0, 0);
        acc1 = __builtin_amdgcn_mfma_f32_16x16x32_f16(a, b1, acc1, 0, 0, 0);
    }
    if (q < 3) {
        #pragma unroll
        for (int r = 0; r < 4; r++) {
            int h = q * 4 + r;
            atomicAdd(&PW[(size_t)i * 1536 + h * 128 + w * 32 + m16],      acc0[r]);
            atomicAdd(&PW[(size_t)i * 1536 + h * 128 + w * 32 + 16 + m16], acc1[r]);
        }
    }
}

// ---------------------------------------------------------------------------
// K5: out GEMM: out += concat @ Wo. A from CAT f16 (k<576) or PW f32 (k>=576).
// grid (6 nt, 12 mt, 6 kz) x 128, atomicAdd (out preset to bo).
// ---------------------------------------------------------------------------
__global__ __launch_bounds__(128) void outgemm_mfma(float* __restrict__ ws, float* __restrict__ out)
{
    const _Float16* catb = (const _Float16*)(ws + OFF_CAT);
    const float* PW = ws + OFF_PW;
    const _Float16* wot = (const _Float16*)(ws + OFF_WOT);

    int t = threadIdx.x, w = t >> 6, lane = t & 63;
    int m = lane & 15, q = lane >> 4;
    int n0 = blockIdx.x * 64;
    int m0 = blockIdx.y * 32 + w * 16;
    int kbase = blockIdx.z * 352;

    f32x4 acc[4] = {0};
    int row = m0 + m;
    #pragma unroll 2
    for (int s = 0; s < 11; s++) {
        int kb = kbase + s * 32;
        int k = kb + q * 8;
        half8 a;
        if (kb < 576) {
            a = *(const half8*)(catb + (size_t)row * 576 + k);
        } else {
            const float* pwp = PW + (size_t)row * 1536 + (k - 576);
            float4 u0 = ((const float4*)pwp)[0];
            float4 u1 = ((const float4*)pwp)[1];
            a[0]=(_Float16)u0.x; a[1]=(_Float16)u0.y; a[2]=(_Float16)u0.z; a[3]=(_Float16)u0.w;
            a[4]=(_Float16)u1.x; a[5]=(_Float16)u1.y; a[6]=(_Float16)u1.z; a[7]=(_Float16)u1.w;
        }
        #pragma unroll
        for (int nt = 0; nt < 4; nt++) {
            half8 b = *(const half8*)(wot + (size_t)(n0 + nt * 16 + m) * 2112 + k);
            acc[nt] = __builtin_amdgcn_mfma_f32_16x16x32_f16(a, b, acc[nt], 0, 0, 0);
        }
    }
    #pragma unroll
    for (int nt = 0; nt < 4; nt++) {
        int col = n0 + nt * 16 + m;
        #pragma unroll
        for (int r = 0; r < 4; r++)
            atomicAdd(&out[(size_t)(m0 + q * 4 + r) * 384 + col], acc[nt][r]);
    }
}

extern "C" void kernel_launch(void* const* d_in, const int* in_sizes, int n_in,
                              void* d_out, int out_size, void* d_ws, size_t ws_size,
                              hipStream_t stream)
{
    const float* s   = (const float*)d_in[0];
    const float* z   = (const float*)d_in[1];
    const float* T   = (const float*)d_in[2];
    const float* Wq  = (const float*)d_in[3];
    const float* bq  = (const float*)d_in[4];
    const float* Wk  = (const float*)d_in[5];
    const float* bk  = (const float*)d_in[6];
    const float* Wv  = (const float*)d_in[7];
    const float* bv  = (const float*)d_in[8];
    const float* Wqp = (const float*)d_in[9];
    const float* bqp = (const float*)d_in[10];
    const float* Wkp = (const float*)d_in[11];
    const float* bkp = (const float*)d_in[12];
    const float* Wvp = (const float*)d_in[13];
    const float* bvp = (const float*)d_in[14];
    const float* Wb  = (const float*)d_in[15];
    const float* bb  = (const float*)d_in[16];
    const float* Wo  = (const float*)d_in[17];
    const float* bo  = (const float*)d_in[18];
    const float* hw  = (const float*)d_in[19];
    float* ws  = (float*)d_ws;
    float* out = (float*)d_out;

    pack_bias<<<2755, 256, 0, stream>>>(s, z, Wq, bq, Wk, bk, Wv, bv,
                                        Wqp, bqp, Wkp, bkp, Wvp, bvp, Wb, bb, Wo, ws);
    proj_mfma<<<dim3(18, 12), 128, 0, stream>>>(ws);
    prep_kernel<<<384, 192, 0, stream>>>(T, hw, ws);
    logits_out40<<<dim3(48, 12), 512, 0, stream>>>(T, bo, ws, out);
    pairwise_mfma<<<dim3(384, 3), 256, 0, stream>>>(z, ws);
    outgemm_mfma<<<dim3(6, 12, 6), 128, 0, stream>>>(ws, out);
}